// Round 2
// baseline (5289.149 us; speedup 1.0000x reference)
//
#include <hip/hip_runtime.h>
#include <hip/hip_bf16.h>

#define N_SUB 100000
#define N_AGR 200000
#define N_URB 100000
#define E_SS  1600000
#define E_AS  400000
#define E_US  200000
#define HID   128
#define DHRU  32
#define NOUT  16
#define NL    3

// ---------------- CSR build ----------------

__global__ void hist_kernel(const int* __restrict__ dst, int* __restrict__ deg, int n) {
    int i = blockIdx.x * 256 + threadIdx.x;
    if (i < n) atomicAdd(&deg[dst[i]], 1);
}

// single-block exclusive scan over deg -> ro, cursor, inv_deg
__global__ void scan_kernel(const int* __restrict__ deg, int* __restrict__ ro,
                            int* __restrict__ cursor, float* __restrict__ inv_deg,
                            int nnodes) {
    __shared__ int sh[256];
    const int tid = threadIdx.x;
    const int per = (nnodes + 255) / 256;
    const int start = tid * per;
    const int end = min(start + per, nnodes);
    int s = 0;
    for (int i = start; i < end; ++i) s += deg[i];
    sh[tid] = s;
    __syncthreads();
    for (int o = 1; o < 256; o <<= 1) {
        int t = (tid >= o) ? sh[tid - o] : 0;
        __syncthreads();
        sh[tid] += t;
        __syncthreads();
    }
    int off = (tid > 0) ? sh[tid - 1] : 0;
    for (int i = start; i < end; ++i) {
        int d = deg[i];
        ro[i] = off;
        cursor[i] = off;
        inv_deg[i] = 1.0f / (float)(d > 1 ? d : 1);
        off += d;
    }
    if (tid == 255) ro[nnodes] = off;
}

__global__ void fill_kernel(const int* __restrict__ src, const int* __restrict__ dst,
                            int* __restrict__ cursor, int* __restrict__ csr, int n) {
    int i = blockIdx.x * 256 + threadIdx.x;
    if (i < n) {
        int d = dst[i];
        int p = atomicAdd(&cursor[d], 1);
        csr[p] = src[i];
    }
}

// ---------------- one-time hru aggregation (layer-invariant) ----------------
// agg2[node][0:32] = sum x_agr over as-edges; agg2[node][32:64] = sum x_urb over us-edges
__global__ void scatter32_kernel(const float* __restrict__ x, const int* __restrict__ src,
                                 const int* __restrict__ dst, float* __restrict__ agg2,
                                 int nE, int off) {
    int t = blockIdx.x * 256 + threadIdx.x;
    int e = t >> 3, j = t & 7;
    if (e >= nE) return;
    int s = src[e], d = dst[e];
    const float4 v = *(const float4*)(x + (size_t)s * 32 + j * 4);
    float* p = agg2 + (size_t)d * 64 + off + j * 4;
    atomicAdd(p + 0, v.x);
    atomicAdd(p + 1, v.y);
    atomicAdd(p + 2, v.z);
    atomicAdd(p + 3, v.w);
}

// ---------------- small weight prep ----------------
__global__ void add3_kernel(const float* __restrict__ a, const float* __restrict__ b,
                            const float* __restrict__ c, float* __restrict__ o, int n) {
    int i = blockIdx.x * 256 + threadIdx.x;
    if (i < n) o[i] = a[i] + b[i] + c[i];
}

// ---------------- per-layer CSR gather aggregation ----------------
// 2 nodes per block, 128 threads (one col each)
__global__ __launch_bounds__(256)
void agg_ss_kernel(const float* __restrict__ h, const int* __restrict__ ro,
                   const int* __restrict__ csr, const float* __restrict__ inv_deg,
                   float* __restrict__ out, int n, int use_mean) {
    int node = blockIdx.x * 2 + (threadIdx.x >> 7);
    int col = threadIdx.x & 127;
    if (node >= n) return;
    int beg = ro[node], end = ro[node + 1];
    float acc = 0.f;
    for (int p = beg; p < end; ++p) {
        int s = csr[p];  // uniform within 128-thread group -> broadcast
        acc += h[(size_t)s * HID + col];
    }
    if (use_mean) acc *= inv_deg[node];
    out[(size_t)node * HID + col] = acc;
}

// ---------------- fused layer GEMM ----------------
// out = relu(agss@Wl + h@Wr_sum + agg2[:, :32]@Wa + agg2[:,32:]@Wu + b_sum)
// tile: 128 rows x 128 cols, 256 threads, 8x8 per thread, K chunks of 32
__global__ __launch_bounds__(256)
void layer_gemm(const float* __restrict__ agss, const float* __restrict__ h,
                const float* __restrict__ agg2, const float* __restrict__ Wl,
                const float* __restrict__ Wr, const float* __restrict__ Wa,
                const float* __restrict__ Wu, const float* __restrict__ bsum,
                float* __restrict__ out, int n) {
    __shared__ float lds_x[32][132];  // transposed [k][row], stride 132 keeps f4 align
    __shared__ float lds_w[32][128];

    const int tid = threadIdx.x;
    const int row0 = blockIdx.x * 128;
    const int tx = tid & 15, ty = tid >> 4;
    const int c0 = tx * 8, r0 = ty * 8;

    float acc[8][8];
#pragma unroll
    for (int r = 0; r < 8; ++r)
#pragma unroll
        for (int c = 0; c < 8; ++c) acc[r][c] = 0.f;

    auto do_seg = [&](const float* __restrict__ X, int ld, const float* __restrict__ W, int K) {
        for (int kb = 0; kb < K; kb += 32) {
            __syncthreads();
            // stage X chunk (transposed): 128 rows x 32 k = 1024 float4 loads
#pragma unroll
            for (int i = 0; i < 4; ++i) {
                int e = tid + i * 256;
                int r = e >> 3, k4 = (e & 7) << 2;
                int gr = row0 + r;
                float4 v = make_float4(0.f, 0.f, 0.f, 0.f);
                if (gr < n) v = *(const float4*)(X + (size_t)gr * ld + kb + k4);
                lds_x[k4 + 0][r] = v.x;
                lds_x[k4 + 1][r] = v.y;
                lds_x[k4 + 2][r] = v.z;
                lds_x[k4 + 3][r] = v.w;
            }
            // stage W chunk: 32 k x 128 cols
#pragma unroll
            for (int i = 0; i < 4; ++i) {
                int e = tid + i * 256;
                int k = e >> 5, c4 = (e & 31) << 2;
                *(float4*)&lds_w[k][c4] = *(const float4*)(W + (size_t)(kb + k) * HID + c4);
            }
            __syncthreads();
#pragma unroll
            for (int k = 0; k < 32; ++k) {
                float4 xa = *(const float4*)&lds_x[k][r0];
                float4 xb = *(const float4*)&lds_x[k][r0 + 4];
                float4 wa = *(const float4*)&lds_w[k][c0];
                float4 wb = *(const float4*)&lds_w[k][c0 + 4];
                float xr[8] = {xa.x, xa.y, xa.z, xa.w, xb.x, xb.y, xb.z, xb.w};
                float wc[8] = {wa.x, wa.y, wa.z, wa.w, wb.x, wb.y, wb.z, wb.w};
#pragma unroll
                for (int r = 0; r < 8; ++r)
#pragma unroll
                    for (int c = 0; c < 8; ++c) acc[r][c] += xr[r] * wc[c];
            }
        }
    };

    do_seg(agss, HID, Wl, HID);
    do_seg(h, HID, Wr, HID);
    do_seg(agg2, 64, Wa, 32);
    do_seg(agg2 + 32, 64, Wu, 32);

    float bias[8];
#pragma unroll
    for (int c = 0; c < 8; ++c) bias[c] = bsum[c0 + c];

#pragma unroll
    for (int r = 0; r < 8; ++r) {
        int gr = row0 + r0 + r;
        if (gr < n) {
            float4 o1, o2;
            o1.x = fmaxf(acc[r][0] + bias[0], 0.f);
            o1.y = fmaxf(acc[r][1] + bias[1], 0.f);
            o1.z = fmaxf(acc[r][2] + bias[2], 0.f);
            o1.w = fmaxf(acc[r][3] + bias[3], 0.f);
            o2.x = fmaxf(acc[r][4] + bias[4], 0.f);
            o2.y = fmaxf(acc[r][5] + bias[5], 0.f);
            o2.z = fmaxf(acc[r][6] + bias[6], 0.f);
            o2.w = fmaxf(acc[r][7] + bias[7], 0.f);
            *(float4*)(out + (size_t)gr * HID + c0) = o1;
            *(float4*)(out + (size_t)gr * HID + c0 + 4) = o2;
        }
    }
}

// ---------------- final projection + softmax ----------------
__global__ void final_kernel(const float* __restrict__ h, const float* __restrict__ Wf,
                             const float* __restrict__ bfv, float* __restrict__ out, int n) {
    int t = blockIdx.x * 256 + threadIdx.x;
    int node = t >> 4;
    int c = t & 15;
    if (node >= n) return;
    const float* hr = h + (size_t)node * HID;
    float acc = bfv[c];
#pragma unroll 4
    for (int k = 0; k < HID; ++k) acc += hr[k] * Wf[k * NOUT + c];
    float m = acc;
#pragma unroll
    for (int o = 8; o >= 1; o >>= 1) m = fmaxf(m, __shfl_xor(m, o, 16));
    float e = expf(acc - m);
    float ssum = e;
#pragma unroll
    for (int o = 8; o >= 1; o >>= 1) ssum += __shfl_xor(ssum, o, 16);
    out[(size_t)node * NOUT + c] = e / ssum;
}

extern "C" void kernel_launch(void* const* d_in, const int* in_sizes, int n_in,
                              void* d_out, int out_size, void* d_ws, size_t ws_size,
                              hipStream_t stream) {
    const float* x_sub = (const float*)d_in[0];
    const float* x_agr = (const float*)d_in[1];
    const float* x_urb = (const float*)d_in[2];
    const int* ss_src = (const int*)d_in[3];
    const int* ss_dst = (const int*)d_in[4];
    const int* as_src = (const int*)d_in[5];
    const int* as_dst = (const int*)d_in[6];
    const int* us_src = (const int*)d_in[7];
    const int* us_dst = (const int*)d_in[8];
    const float* Wl_ss = (const float*)d_in[9];
    const float* bl_ss = (const float*)d_in[10];
    const float* Wr_ss = (const float*)d_in[11];
    const float* Wl_as = (const float*)d_in[12];
    const float* bl_as = (const float*)d_in[13];
    const float* Wr_as = (const float*)d_in[14];
    const float* Wl_us = (const float*)d_in[15];
    const float* bl_us = (const float*)d_in[16];
    const float* Wr_us = (const float*)d_in[17];
    const float* Wf = (const float*)d_in[18];
    const float* bfv = (const float*)d_in[19];
    float* out = (float*)d_out;

    char* ws = (char*)d_ws;
    float* bufA = (float*)(ws + 0);                    // 51,200,000 B
    float* bufB = (float*)(ws + 51200000);             // 51,200,000 B
    float* agg2 = (float*)(ws + 102400000);            // 25,600,000 B
    float* inv_deg = (float*)(ws + 128000000);         //    400,000 B
    int* ro = (int*)(ws + 128400000);                  //    400,016 B
    int* cursor = (int*)(ws + 128800016);              //    400,000 B
    int* deg = (int*)(ws + 129200016);                 //    400,000 B
    int* csr = (int*)(ws + 129600016);                 //  6,400,000 B
    float* Wr_sum = (float*)(ws + 136000016);          //    196,608 B
    float* b_sum = (float*)(ws + 136196624);           //      1,536 B

    // ---- CSR build (sub->sub) ----
    hipMemsetAsync(deg, 0, N_SUB * sizeof(int), stream);
    hist_kernel<<<(E_SS + 255) / 256, 256, 0, stream>>>(ss_dst, deg, E_SS);
    scan_kernel<<<1, 256, 0, stream>>>(deg, ro, cursor, inv_deg, N_SUB);
    fill_kernel<<<(E_SS + 255) / 256, 256, 0, stream>>>(ss_src, ss_dst, cursor, csr, E_SS);

    // ---- layer-invariant hru aggregations ----
    hipMemsetAsync(agg2, 0, (size_t)N_SUB * 64 * sizeof(float), stream);
    scatter32_kernel<<<(E_AS * 8 + 255) / 256, 256, 0, stream>>>(x_agr, as_src, as_dst, agg2, E_AS, 0);
    scatter32_kernel<<<(E_US * 8 + 255) / 256, 256, 0, stream>>>(x_urb, us_src, us_dst, agg2, E_US, 32);

    // ---- combined root weights + biases ----
    add3_kernel<<<(NL * HID * HID + 255) / 256, 256, 0, stream>>>(Wr_ss, Wr_as, Wr_us, Wr_sum, NL * HID * HID);
    add3_kernel<<<(NL * HID + 255) / 256, 256, 0, stream>>>(bl_ss, bl_as, bl_us, b_sum, NL * HID);

    const int gemm_grid = (N_SUB + 127) / 128;
    const int agg_grid = (N_SUB + 1) / 2;

    // ---- layer 0: h = x_sub, sum aggregation ----
    agg_ss_kernel<<<agg_grid, 256, 0, stream>>>(x_sub, ro, csr, inv_deg, bufA, N_SUB, 0);
    layer_gemm<<<gemm_grid, 256, 0, stream>>>(bufA, x_sub, agg2,
                                              Wl_ss + 0 * HID * HID, Wr_sum + 0 * HID * HID,
                                              Wl_as + 0 * DHRU * HID, Wl_us + 0 * DHRU * HID,
                                              b_sum + 0 * HID, bufB, N_SUB);

    // ---- layer 1: h = bufB, mean aggregation, out in-place into bufA ----
    agg_ss_kernel<<<agg_grid, 256, 0, stream>>>(bufB, ro, csr, inv_deg, bufA, N_SUB, 1);
    layer_gemm<<<gemm_grid, 256, 0, stream>>>(bufA, bufB, agg2,
                                              Wl_ss + 1 * HID * HID, Wr_sum + 1 * HID * HID,
                                              Wl_as + 1 * DHRU * HID, Wl_us + 1 * DHRU * HID,
                                              b_sum + 1 * HID, bufA, N_SUB);

    // ---- layer 2: h = bufA, mean aggregation, out in-place into bufB ----
    agg_ss_kernel<<<agg_grid, 256, 0, stream>>>(bufA, ro, csr, inv_deg, bufB, N_SUB, 1);
    layer_gemm<<<gemm_grid, 256, 0, stream>>>(bufB, bufA, agg2,
                                              Wl_ss + 2 * HID * HID, Wr_sum + 2 * HID * HID,
                                              Wl_as + 2 * DHRU * HID, Wl_us + 2 * DHRU * HID,
                                              b_sum + 2 * HID, bufB, N_SUB);

    // ---- final projection + softmax ----
    final_kernel<<<(N_SUB * NOUT + 255) / 256, 256, 0, stream>>>(bufB, Wf, bfv, out, N_SUB);
}

// Round 3
// 1184.942 us; speedup vs baseline: 4.4636x; 4.4636x over previous
//
#include <hip/hip_runtime.h>
#include <hip/hip_bf16.h>

#define N_SUB 100000
#define N_AGR 200000
#define N_URB 100000
#define E_SS  1600000
#define E_AS  400000
#define E_US  200000
#define HID   128
#define DHRU  32
#define NOUT  16
#define NL    3

typedef unsigned short u16;
typedef unsigned int u32;
typedef short bf16x8 __attribute__((ext_vector_type(8)));
typedef float f32x4 __attribute__((ext_vector_type(4)));

static __device__ __forceinline__ u16 f2b(float f) {
    u32 x = __float_as_uint(f);
    u32 r = (x + 0x7fffu + ((x >> 16) & 1u)) >> 16;  // RNE
    return (u16)r;
}
static __device__ __forceinline__ float blo(u32 u) { return __uint_as_float(u << 16); }
static __device__ __forceinline__ float bhi(u32 u) { return __uint_as_float(u & 0xffff0000u); }

// ---------------- CSR build ----------------

__global__ void hist_kernel(const int* __restrict__ dst, int* __restrict__ deg, int n) {
    int i = blockIdx.x * 256 + threadIdx.x;
    if (i < n) atomicAdd(&deg[dst[i]], 1);
}

// single-block exclusive scan; degcur holds deg on entry, cursor on exit
__global__ void scan_kernel(int* degcur, int* __restrict__ ro,
                            float* __restrict__ inv_deg, int nnodes) {
    __shared__ int sh[256];
    const int tid = threadIdx.x;
    const int per = (nnodes + 255) / 256;
    const int start = tid * per;
    const int end = min(start + per, nnodes);
    int s = 0;
    for (int i = start; i < end; ++i) s += degcur[i];
    sh[tid] = s;
    __syncthreads();
    for (int o = 1; o < 256; o <<= 1) {
        int t = (tid >= o) ? sh[tid - o] : 0;
        __syncthreads();
        sh[tid] += t;
        __syncthreads();
    }
    int off = (tid > 0) ? sh[tid - 1] : 0;
    for (int i = start; i < end; ++i) {
        int d = degcur[i];
        ro[i] = off;
        inv_deg[i] = 1.0f / (float)(d > 1 ? d : 1);
        degcur[i] = off;  // cursor
        off += d;
    }
    if (tid == 255) ro[nnodes] = off;
}

__global__ void fill_kernel(const int* __restrict__ src, const int* __restrict__ dst,
                            int* __restrict__ cursor, int* __restrict__ csr, int n) {
    int i = blockIdx.x * 256 + threadIdx.x;
    if (i < n) {
        int p = atomicAdd(&cursor[dst[i]], 1);
        csr[p] = src[i];
    }
}

// ---------------- one-time hru aggregation (fp32 atomics) ----------------
__global__ void scatter32_kernel(const float* __restrict__ x, const int* __restrict__ src,
                                 const int* __restrict__ dst, float* __restrict__ agg2,
                                 int nE, int off) {
    int t = blockIdx.x * 256 + threadIdx.x;
    int e = t >> 3, j = t & 7;
    if (e >= nE) return;
    int s = src[e], d = dst[e];
    const float4 v = *(const float4*)(x + (size_t)s * 32 + j * 4);
    float* p = agg2 + (size_t)d * 64 + off + j * 4;
    atomicAdd(p + 0, v.x);
    atomicAdd(p + 1, v.y);
    atomicAdd(p + 2, v.z);
    atomicAdd(p + 3, v.w);
}

// ---------------- weight prep ----------------
__global__ void add3_kernel(const float* __restrict__ a, const float* __restrict__ b,
                            const float* __restrict__ c, float* __restrict__ o, int n) {
    int i = blockIdx.x * 256 + threadIdx.x;
    if (i < n) o[i] = a[i] + b[i] + c[i];
}

// Pack stacked [Wl_ss; Wr_ss+Wr_as+Wr_us; Wl_as; Wl_us] (320x128) per layer into
// MFMA B-fragment order: Bp[lay][((s*8+c)*64+lane)*8+j] = W[s*32+(lane>>4)*8+j][c*16+(lane&15)]
__global__ void build_bp(const float* __restrict__ Wl_ss, const float* __restrict__ Wr_ss,
                         const float* __restrict__ Wr_as, const float* __restrict__ Wr_us,
                         const float* __restrict__ Wl_as, const float* __restrict__ Wl_us,
                         u16* __restrict__ Bp) {
    int b = blockIdx.x;           // 3*10*8 = 240
    int lane = threadIdx.x;       // 64
    int lay = b / 80, rem = b % 80, s = rem / 8, c = rem % 8;
    int col = c * 16 + (lane & 15);
    u16* o = Bp + (size_t)(((lay * 80) + s * 8 + c) * 64 + lane) * 8;
#pragma unroll
    for (int j = 0; j < 8; ++j) {
        int k = s * 32 + (lane >> 4) * 8 + j;
        float v;
        if (k < 128) {
            v = Wl_ss[((size_t)lay * 128 + k) * 128 + col];
        } else if (k < 256) {
            size_t idx = ((size_t)lay * 128 + (k - 128)) * 128 + col;
            v = Wr_ss[idx] + Wr_as[idx] + Wr_us[idx];
        } else if (k < 288) {
            v = Wl_as[((size_t)lay * 32 + (k - 256)) * 128 + col];
        } else {
            v = Wl_us[((size_t)lay * 32 + (k - 288)) * 128 + col];
        }
        o[j] = f2b(v);
    }
}

// ---------------- fp32 -> bf16 convert (x_sub -> h0) ----------------
__global__ void cvt_f32_bf16(const float* __restrict__ in, u16* __restrict__ o, int n4) {
    int i = blockIdx.x * 256 + threadIdx.x;
    if (i >= n4) return;
    float4 v = ((const float4*)in)[i];
    ushort4 u;
    u.x = f2b(v.x); u.y = f2b(v.y); u.z = f2b(v.z); u.w = f2b(v.w);
    ((ushort4*)o)[i] = u;
}

// ---------------- per-layer CSR gather aggregation (bf16 in/out, fp32 accum) ----------------
// one wave per node; lane handles 2 cols (one u32 = 2 bf16)
__global__ __launch_bounds__(256)
void agg_ss_bf16(const u32* __restrict__ h32, const int* __restrict__ ro,
                 const int* __restrict__ csr, const float* __restrict__ inv_deg,
                 u32* __restrict__ out32, int n, int use_mean) {
    int node = blockIdx.x * 4 + (threadIdx.x >> 6);
    int lane = threadIdx.x & 63;
    if (node >= n) return;
    int beg = ro[node], end = ro[node + 1];
    float a0 = 0.f, a1 = 0.f;
    int p = beg;
    for (; p + 1 < end; p += 2) {
        int s0 = csr[p], s1 = csr[p + 1];
        u32 u0 = h32[(size_t)s0 * 64 + lane];
        u32 u1 = h32[(size_t)s1 * 64 + lane];
        a0 += blo(u0) + blo(u1);
        a1 += bhi(u0) + bhi(u1);
    }
    if (p < end) {
        u32 u0 = h32[(size_t)csr[p] * 64 + lane];
        a0 += blo(u0);
        a1 += bhi(u0);
    }
    if (use_mean) {
        float iv = inv_deg[node];
        a0 *= iv; a1 *= iv;
    }
    out32[(size_t)node * 64 + lane] = (u32)f2b(a0) | ((u32)f2b(a1) << 16);
}

// ---------------- fused layer GEMM via MFMA bf16 ----------------
// out[row][0:128] = relu([agss|h|agg2] @ Bp + bsum), row-block 128, 4 waves x 32 rows
__global__ __launch_bounds__(256)
void layer_gemm_mfma(const u16* __restrict__ agss, const u16* __restrict__ h,
                     const float* __restrict__ agg2, const u16* __restrict__ Bp,
                     const float* __restrict__ bsum, u16* __restrict__ out, int n) {
    __shared__ __align__(16) u16 tile[4][32][136];
    const int tid = threadIdx.x;
    const int w = tid >> 6, l = tid & 63;
    const int lr = l & 15, lq = l >> 4;
    const int rows0 = blockIdx.x * 128 + w * 32;

    f32x4 acc[2][8];
#pragma unroll
    for (int rf = 0; rf < 2; ++rf)
#pragma unroll
        for (int c = 0; c < 8; ++c) acc[rf][c] = (f32x4){0.f, 0.f, 0.f, 0.f};

    const bf16x8 zf = {0, 0, 0, 0, 0, 0, 0, 0};

#pragma unroll
    for (int s = 0; s < 10; ++s) {
        bf16x8 a[2];
        if (s < 8) {
            const u16* X = (s < 4) ? agss : h;
            int koff = (s & 3) * 32 + lq * 8;
#pragma unroll
            for (int rf = 0; rf < 2; ++rf) {
                int row = rows0 + rf * 16 + lr;
                a[rf] = (row < n) ? *(const bf16x8*)(X + (size_t)row * 128 + koff) : zf;
            }
        } else {
            int koff = (s - 8) * 32 + lq * 8;
#pragma unroll
            for (int rf = 0; rf < 2; ++rf) {
                int row = rows0 + rf * 16 + lr;
                if (row < n) {
                    float4 f0 = *(const float4*)(agg2 + (size_t)row * 64 + koff);
                    float4 f1 = *(const float4*)(agg2 + (size_t)row * 64 + koff + 4);
                    bf16x8 v;
                    v[0] = (short)f2b(f0.x); v[1] = (short)f2b(f0.y);
                    v[2] = (short)f2b(f0.z); v[3] = (short)f2b(f0.w);
                    v[4] = (short)f2b(f1.x); v[5] = (short)f2b(f1.y);
                    v[6] = (short)f2b(f1.z); v[7] = (short)f2b(f1.w);
                    a[rf] = v;
                } else {
                    a[rf] = zf;
                }
            }
        }
        const u16* bp = Bp + ((size_t)(s * 8) * 64 + l) * 8;
#pragma unroll
        for (int c = 0; c < 8; ++c) {
            bf16x8 b = *(const bf16x8*)(bp + (size_t)c * 64 * 8);
            acc[0][c] = __builtin_amdgcn_mfma_f32_16x16x32_bf16(a[0], b, acc[0][c], 0, 0, 0);
            acc[1][c] = __builtin_amdgcn_mfma_f32_16x16x32_bf16(a[1], b, acc[1][c], 0, 0, 0);
        }
    }

    float bias[8];
#pragma unroll
    for (int c = 0; c < 8; ++c) bias[c] = bsum[c * 16 + lr];

#pragma unroll
    for (int rf = 0; rf < 2; ++rf)
#pragma unroll
        for (int c = 0; c < 8; ++c)
#pragma unroll
            for (int r = 0; r < 4; ++r) {
                float v = fmaxf(acc[rf][c][r] + bias[c], 0.f);
                tile[w][rf * 16 + lq * 4 + r][c * 16 + lr] = f2b(v);
            }

    // coalesced bf16 store: 8 iters x (4 rows x 128 cols)
#pragma unroll
    for (int i = 0; i < 8; ++i) {
        int row = i * 4 + lq;
        int grow = rows0 + row;
        if (grow < n)
            *(bf16x8*)(out + (size_t)grow * 128 + lr * 8) =
                *(const bf16x8*)&tile[w][row][lr * 8];
    }
}

// ---------------- final projection + softmax (bf16 h, fp32 out) ----------------
__global__ __launch_bounds__(256)
void final_kernel(const u32* __restrict__ h32, const float* __restrict__ Wf,
                  const float* __restrict__ bfv, float* __restrict__ out, int n) {
    __shared__ float wsh[HID * NOUT + NOUT];
    for (int i = threadIdx.x; i < HID * NOUT; i += 256) wsh[i] = Wf[i];
    if (threadIdx.x < NOUT) wsh[HID * NOUT + threadIdx.x] = bfv[threadIdx.x];
    __syncthreads();
    int t = blockIdx.x * 256 + threadIdx.x;
    int node = t >> 4, c = t & 15;
    if (node >= n) return;
    const u32* hr = h32 + (size_t)node * 64;
    float acc = wsh[HID * NOUT + c];
#pragma unroll 4
    for (int k2 = 0; k2 < 64; ++k2) {
        u32 u = hr[k2];
        acc += blo(u) * wsh[(2 * k2) * NOUT + c] + bhi(u) * wsh[(2 * k2 + 1) * NOUT + c];
    }
    float m = acc;
#pragma unroll
    for (int o = 8; o >= 1; o >>= 1) m = fmaxf(m, __shfl_xor(m, o, 16));
    float e = expf(acc - m);
    float ssum = e;
#pragma unroll
    for (int o = 8; o >= 1; o >>= 1) ssum += __shfl_xor(ssum, o, 16);
    out[(size_t)node * NOUT + c] = e / ssum;
}

extern "C" void kernel_launch(void* const* d_in, const int* in_sizes, int n_in,
                              void* d_out, int out_size, void* d_ws, size_t ws_size,
                              hipStream_t stream) {
    const float* x_sub = (const float*)d_in[0];
    const int* ss_src = (const int*)d_in[3];
    const int* ss_dst = (const int*)d_in[4];
    const int* as_src = (const int*)d_in[5];
    const int* as_dst = (const int*)d_in[6];
    const int* us_src = (const int*)d_in[7];
    const int* us_dst = (const int*)d_in[8];
    const float* x_agr = (const float*)d_in[1];
    const float* x_urb = (const float*)d_in[2];
    const float* Wl_ss = (const float*)d_in[9];
    const float* bl_ss = (const float*)d_in[10];
    const float* Wr_ss = (const float*)d_in[11];
    const float* Wl_as = (const float*)d_in[12];
    const float* bl_as = (const float*)d_in[13];
    const float* Wr_as = (const float*)d_in[14];
    const float* Wl_us = (const float*)d_in[15];
    const float* bl_us = (const float*)d_in[16];
    const float* Wr_us = (const float*)d_in[17];
    const float* Wf = (const float*)d_in[18];
    const float* bfv = (const float*)d_in[19];
    float* out = (float*)d_out;

    char* ws = (char*)d_ws;
    u16* h0     = (u16*)(ws + 0);            // 25,600,000
    u16* hA     = (u16*)(ws + 25600000);     // 25,600,000
    u16* hB     = (u16*)(ws + 51200000);     // 25,600,000
    u16* agss   = (u16*)(ws + 76800000);     // 25,600,000
    float* agg2f = (float*)(ws + 102400000); // 25,600,000
    float* inv_deg = (float*)(ws + 128000000); // 400,000
    int* ro     = (int*)(ws + 128400000);    // 400,016
    int* degcur = (int*)(ws + 128800016);    // 400,000
    int* csr    = (int*)(ws + 129200016);    // 6,400,000
    u16* Bp     = (u16*)(ws + 135600016);    // 245,760
    float* b_sum = (float*)(ws + 135845776); // 1,536

    // ---- CSR build (sub->sub) ----
    hipMemsetAsync(degcur, 0, N_SUB * sizeof(int), stream);
    hist_kernel<<<(E_SS + 255) / 256, 256, 0, stream>>>(ss_dst, degcur, E_SS);
    scan_kernel<<<1, 256, 0, stream>>>(degcur, ro, inv_deg, N_SUB);
    fill_kernel<<<(E_SS + 255) / 256, 256, 0, stream>>>(ss_src, ss_dst, degcur, csr, E_SS);

    // ---- layer-invariant hru aggregations (fp32) ----
    hipMemsetAsync(agg2f, 0, (size_t)N_SUB * 64 * sizeof(float), stream);
    scatter32_kernel<<<(E_AS * 8 + 255) / 256, 256, 0, stream>>>(x_agr, as_src, as_dst, agg2f, E_AS, 0);
    scatter32_kernel<<<(E_US * 8 + 255) / 256, 256, 0, stream>>>(x_urb, us_src, us_dst, agg2f, E_US, 32);

    // ---- weight packing + bias sums ----
    build_bp<<<240, 64, 0, stream>>>(Wl_ss, Wr_ss, Wr_as, Wr_us, Wl_as, Wl_us, Bp);
    add3_kernel<<<2, 256, 0, stream>>>(bl_ss, bl_as, bl_us, b_sum, NL * HID);

    // ---- x_sub -> bf16 ----
    cvt_f32_bf16<<<(N_SUB * HID / 4 + 255) / 256, 256, 0, stream>>>(x_sub, h0, N_SUB * HID / 4);

    const int agg_grid = (N_SUB + 3) / 4;
    const int gemm_grid = (N_SUB + 127) / 128;
    const size_t BPL = 40960;  // Bp per-layer stride (u16)

    // ---- layer 0: sum aggregation ----
    agg_ss_bf16<<<agg_grid, 256, 0, stream>>>((const u32*)h0, ro, csr, inv_deg, (u32*)agss, N_SUB, 0);
    layer_gemm_mfma<<<gemm_grid, 256, 0, stream>>>(agss, h0, agg2f, Bp + 0 * BPL, b_sum + 0 * HID, hA, N_SUB);

    // ---- layer 1: mean aggregation ----
    agg_ss_bf16<<<agg_grid, 256, 0, stream>>>((const u32*)hA, ro, csr, inv_deg, (u32*)agss, N_SUB, 1);
    layer_gemm_mfma<<<gemm_grid, 256, 0, stream>>>(agss, hA, agg2f, Bp + 1 * BPL, b_sum + 1 * HID, hB, N_SUB);

    // ---- layer 2: mean aggregation ----
    agg_ss_bf16<<<agg_grid, 256, 0, stream>>>((const u32*)hB, ro, csr, inv_deg, (u32*)agss, N_SUB, 1);
    layer_gemm_mfma<<<gemm_grid, 256, 0, stream>>>(agss, hB, agg2f, Bp + 2 * BPL, b_sum + 2 * HID, hA, N_SUB);

    // ---- final projection + softmax ----
    final_kernel<<<(N_SUB * NOUT + 255) / 256, 256, 0, stream>>>((const u32*)hA, Wf, bfv, out, N_SUB);
}

// Round 4
// 930.427 us; speedup vs baseline: 5.6846x; 1.2735x over previous
//
#include <hip/hip_runtime.h>
#include <hip/hip_bf16.h>

#define N_SUB 100000
#define N_AGR 200000
#define N_URB 100000
#define E_SS  1600000
#define E_AS  400000
#define E_US  200000
#define HID   128
#define DHRU  32
#define NOUT  16
#define NL    3
#define SCAN_T 12500  // N_SUB / 8

typedef unsigned short u16;
typedef unsigned int u32;
typedef short bf16x8 __attribute__((ext_vector_type(8)));
typedef float f32x4 __attribute__((ext_vector_type(4)));

static __device__ __forceinline__ u16 f2b(float f) {
    u32 x = __float_as_uint(f);
    u32 r = (x + 0x7fffu + ((x >> 16) & 1u)) >> 16;  // RNE
    return (u16)r;
}
static __device__ __forceinline__ float blo(u32 u) { return __uint_as_float(u << 16); }
static __device__ __forceinline__ float bhi(u32 u) { return __uint_as_float(u & 0xffff0000u); }

// ---------------- CSR build ----------------

__global__ void hist_kernel(const int* __restrict__ dst, int* __restrict__ deg, int n) {
    int i = blockIdx.x * 256 + threadIdx.x;
    if (i < n) atomicAdd(&deg[dst[i]], 1);
}

// 3-phase parallel exclusive scan over deg[N_SUB]
__global__ void scan_p1(const int* __restrict__ deg, int* __restrict__ tsum) {
    int i = blockIdx.x * 256 + threadIdx.x;
    if (i >= SCAN_T) return;
    const int4* p = (const int4*)(deg + i * 8);
    int4 a = p[0], b = p[1];
    tsum[i] = a.x + a.y + a.z + a.w + b.x + b.y + b.z + b.w;
}

__global__ void scan_p2(int* __restrict__ tsum) {
    __shared__ int sh[256];
    const int tid = threadIdx.x;
    const int start = tid * 49;
    const int end = min(start + 49, SCAN_T);
    int s = 0;
    for (int i = start; i < end; ++i) s += tsum[i];
    sh[tid] = s;
    __syncthreads();
    for (int o = 1; o < 256; o <<= 1) {
        int t = (tid >= o) ? sh[tid - o] : 0;
        __syncthreads();
        sh[tid] += t;
        __syncthreads();
    }
    int off = (tid > 0) ? sh[tid - 1] : 0;
    for (int i = start; i < end; ++i) {
        int v = tsum[i];
        tsum[i] = off;
        off += v;
    }
}

// degcur: deg on entry, cursor on exit (in-place, one thread per 8 nodes)
__global__ void scan_p3(int* __restrict__ degcur, const int* __restrict__ tsum,
                        int* __restrict__ ro, float* __restrict__ inv_deg) {
    int i = blockIdx.x * 256 + threadIdx.x;
    if (i >= SCAN_T) return;
    int off = tsum[i];
#pragma unroll
    for (int j = 0; j < 8; ++j) {
        int idx = i * 8 + j;
        int d = degcur[idx];
        ro[idx] = off;
        inv_deg[idx] = 1.0f / (float)(d > 1 ? d : 1);
        degcur[idx] = off;  // cursor
        off += d;
    }
    if (i == SCAN_T - 1) ro[N_SUB] = off;
}

__global__ void fill_kernel(const int* __restrict__ src, const int* __restrict__ dst,
                            int* __restrict__ cursor, int* __restrict__ csr, int n) {
    int i = blockIdx.x * 256 + threadIdx.x;
    if (i < n) {
        int p = atomicAdd(&cursor[dst[i]], 1);
        csr[p] = src[i];
    }
}

// ---------------- one-time hru aggregation (fp32 atomics) ----------------
__global__ void scatter32_kernel(const float* __restrict__ x, const int* __restrict__ src,
                                 const int* __restrict__ dst, float* __restrict__ agg2,
                                 int nE, int off) {
    int t = blockIdx.x * 256 + threadIdx.x;
    int e = t >> 3, j = t & 7;
    if (e >= nE) return;
    int s = src[e], d = dst[e];
    const float4 v = *(const float4*)(x + (size_t)s * 32 + j * 4);
    float* p = agg2 + (size_t)d * 64 + off + j * 4;
    atomicAdd(p + 0, v.x);
    atomicAdd(p + 1, v.y);
    atomicAdd(p + 2, v.z);
    atomicAdd(p + 3, v.w);
}

// ---------------- weight prep ----------------
__global__ void add3_kernel(const float* __restrict__ a, const float* __restrict__ b,
                            const float* __restrict__ c, float* __restrict__ o, int n) {
    int i = blockIdx.x * 256 + threadIdx.x;
    if (i < n) o[i] = a[i] + b[i] + c[i];
}

// Pack stacked [Wl_ss; Wr_ss+Wr_as+Wr_us; Wl_as; Wl_us] (320x128) per layer into
// MFMA B-fragment order: Bp[lay][((s*8+c)*64+lane)*8+j] = W[s*32+(lane>>4)*8+j][c*16+(lane&15)]
__global__ void build_bp(const float* __restrict__ Wl_ss, const float* __restrict__ Wr_ss,
                         const float* __restrict__ Wr_as, const float* __restrict__ Wr_us,
                         const float* __restrict__ Wl_as, const float* __restrict__ Wl_us,
                         u16* __restrict__ Bp) {
    int b = blockIdx.x;           // 3*10*8 = 240
    int lane = threadIdx.x;       // 64
    int lay = b / 80, rem = b % 80, s = rem / 8, c = rem % 8;
    int col = c * 16 + (lane & 15);
    u16* o = Bp + (size_t)(((lay * 80) + s * 8 + c) * 64 + lane) * 8;
#pragma unroll
    for (int j = 0; j < 8; ++j) {
        int k = s * 32 + (lane >> 4) * 8 + j;
        float v;
        if (k < 128) {
            v = Wl_ss[((size_t)lay * 128 + k) * 128 + col];
        } else if (k < 256) {
            size_t idx = ((size_t)lay * 128 + (k - 128)) * 128 + col;
            v = Wr_ss[idx] + Wr_as[idx] + Wr_us[idx];
        } else if (k < 288) {
            v = Wl_as[((size_t)lay * 32 + (k - 256)) * 128 + col];
        } else {
            v = Wl_us[((size_t)lay * 32 + (k - 288)) * 128 + col];
        }
        o[j] = f2b(v);
    }
}

// ---------------- fp32 -> bf16 convert (x_sub -> h0) ----------------
__global__ void cvt_f32_bf16(const float* __restrict__ in, u16* __restrict__ o, int n4) {
    int i = blockIdx.x * 256 + threadIdx.x;
    if (i >= n4) return;
    float4 v = ((const float4*)in)[i];
    ushort4 u;
    u.x = f2b(v.x); u.y = f2b(v.y); u.z = f2b(v.z); u.w = f2b(v.w);
    ((ushort4*)o)[i] = u;
}

// ---------------- per-layer CSR gather aggregation (bf16 in/out, fp32 accum) ----------------
__global__ __launch_bounds__(256)
void agg_ss_bf16(const u32* __restrict__ h32, const int* __restrict__ ro,
                 const int* __restrict__ csr, const float* __restrict__ inv_deg,
                 u32* __restrict__ out32, int n, int use_mean) {
    int node = blockIdx.x * 4 + (threadIdx.x >> 6);
    int lane = threadIdx.x & 63;
    if (node >= n) return;
    int beg = ro[node], end = ro[node + 1];
    float a0 = 0.f, a1 = 0.f;
    int p = beg;
    for (; p + 1 < end; p += 2) {
        int s0 = csr[p], s1 = csr[p + 1];
        u32 u0 = h32[(size_t)s0 * 64 + lane];
        u32 u1 = h32[(size_t)s1 * 64 + lane];
        a0 += blo(u0) + blo(u1);
        a1 += bhi(u0) + bhi(u1);
    }
    if (p < end) {
        u32 u0 = h32[(size_t)csr[p] * 64 + lane];
        a0 += blo(u0);
        a1 += bhi(u0);
    }
    if (use_mean) {
        float iv = inv_deg[node];
        a0 *= iv; a1 *= iv;
    }
    out32[(size_t)node * 64 + lane] = (u32)f2b(a0) | ((u32)f2b(a1) << 16);
}

// ---------------- fused layer GEMM via MFMA bf16 ----------------
__global__ __launch_bounds__(256)
void layer_gemm_mfma(const u16* __restrict__ agss, const u16* __restrict__ h,
                     const float* __restrict__ agg2, const u16* __restrict__ Bp,
                     const float* __restrict__ bsum, u16* __restrict__ out, int n) {
    __shared__ __align__(16) u16 tile[4][32][136];
    const int tid = threadIdx.x;
    const int w = tid >> 6, l = tid & 63;
    const int lr = l & 15, lq = l >> 4;
    const int rows0 = blockIdx.x * 128 + w * 32;

    f32x4 acc[2][8];
#pragma unroll
    for (int rf = 0; rf < 2; ++rf)
#pragma unroll
        for (int c = 0; c < 8; ++c) acc[rf][c] = (f32x4){0.f, 0.f, 0.f, 0.f};

    const bf16x8 zf = {0, 0, 0, 0, 0, 0, 0, 0};

#pragma unroll
    for (int s = 0; s < 10; ++s) {
        bf16x8 a[2];
        if (s < 8) {
            const u16* X = (s < 4) ? agss : h;
            int koff = (s & 3) * 32 + lq * 8;
#pragma unroll
            for (int rf = 0; rf < 2; ++rf) {
                int row = rows0 + rf * 16 + lr;
                a[rf] = (row < n) ? *(const bf16x8*)(X + (size_t)row * 128 + koff) : zf;
            }
        } else {
            int koff = (s - 8) * 32 + lq * 8;
#pragma unroll
            for (int rf = 0; rf < 2; ++rf) {
                int row = rows0 + rf * 16 + lr;
                if (row < n) {
                    float4 f0 = *(const float4*)(agg2 + (size_t)row * 64 + koff);
                    float4 f1 = *(const float4*)(agg2 + (size_t)row * 64 + koff + 4);
                    bf16x8 v;
                    v[0] = (short)f2b(f0.x); v[1] = (short)f2b(f0.y);
                    v[2] = (short)f2b(f0.z); v[3] = (short)f2b(f0.w);
                    v[4] = (short)f2b(f1.x); v[5] = (short)f2b(f1.y);
                    v[6] = (short)f2b(f1.z); v[7] = (short)f2b(f1.w);
                    a[rf] = v;
                } else {
                    a[rf] = zf;
                }
            }
        }
        const u16* bp = Bp + ((size_t)(s * 8) * 64 + l) * 8;
#pragma unroll
        for (int c = 0; c < 8; ++c) {
            bf16x8 b = *(const bf16x8*)(bp + (size_t)c * 64 * 8);
            acc[0][c] = __builtin_amdgcn_mfma_f32_16x16x32_bf16(a[0], b, acc[0][c], 0, 0, 0);
            acc[1][c] = __builtin_amdgcn_mfma_f32_16x16x32_bf16(a[1], b, acc[1][c], 0, 0, 0);
        }
    }

    float bias[8];
#pragma unroll
    for (int c = 0; c < 8; ++c) bias[c] = bsum[c * 16 + lr];

#pragma unroll
    for (int rf = 0; rf < 2; ++rf)
#pragma unroll
        for (int c = 0; c < 8; ++c)
#pragma unroll
            for (int r = 0; r < 4; ++r) {
                float v = fmaxf(acc[rf][c][r] + bias[c], 0.f);
                tile[w][rf * 16 + lq * 4 + r][c * 16 + lr] = f2b(v);
            }

#pragma unroll
    for (int i = 0; i < 8; ++i) {
        int row = i * 4 + lq;
        int grow = rows0 + row;
        if (grow < n)
            *(bf16x8*)(out + (size_t)grow * 128 + lr * 8) =
                *(const bf16x8*)&tile[w][row][lr * 8];
    }
}

// ---------------- final projection + softmax (bf16 h, fp32 out) ----------------
__global__ __launch_bounds__(256)
void final_kernel(const u32* __restrict__ h32, const float* __restrict__ Wf,
                  const float* __restrict__ bfv, float* __restrict__ out, int n) {
    __shared__ float wsh[HID * NOUT + NOUT];
    for (int i = threadIdx.x; i < HID * NOUT; i += 256) wsh[i] = Wf[i];
    if (threadIdx.x < NOUT) wsh[HID * NOUT + threadIdx.x] = bfv[threadIdx.x];
    __syncthreads();
    int t = blockIdx.x * 256 + threadIdx.x;
    int node = t >> 4, c = t & 15;
    if (node >= n) return;
    const u32* hr = h32 + (size_t)node * 64;
    float acc = wsh[HID * NOUT + c];
#pragma unroll 4
    for (int k2 = 0; k2 < 64; ++k2) {
        u32 u = hr[k2];
        acc += blo(u) * wsh[(2 * k2) * NOUT + c] + bhi(u) * wsh[(2 * k2 + 1) * NOUT + c];
    }
    float m = acc;
#pragma unroll
    for (int o = 8; o >= 1; o >>= 1) m = fmaxf(m, __shfl_xor(m, o, 16));
    float e = expf(acc - m);
    float ssum = e;
#pragma unroll
    for (int o = 8; o >= 1; o >>= 1) ssum += __shfl_xor(ssum, o, 16);
    out[(size_t)node * NOUT + c] = e / ssum;
}

extern "C" void kernel_launch(void* const* d_in, const int* in_sizes, int n_in,
                              void* d_out, int out_size, void* d_ws, size_t ws_size,
                              hipStream_t stream) {
    const float* x_sub = (const float*)d_in[0];
    const float* x_agr = (const float*)d_in[1];
    const float* x_urb = (const float*)d_in[2];
    const int* ss_src = (const int*)d_in[3];
    const int* ss_dst = (const int*)d_in[4];
    const int* as_src = (const int*)d_in[5];
    const int* as_dst = (const int*)d_in[6];
    const int* us_src = (const int*)d_in[7];
    const int* us_dst = (const int*)d_in[8];
    const float* Wl_ss = (const float*)d_in[9];
    const float* bl_ss = (const float*)d_in[10];
    const float* Wr_ss = (const float*)d_in[11];
    const float* Wl_as = (const float*)d_in[12];
    const float* bl_as = (const float*)d_in[13];
    const float* Wr_as = (const float*)d_in[14];
    const float* Wl_us = (const float*)d_in[15];
    const float* bl_us = (const float*)d_in[16];
    const float* Wr_us = (const float*)d_in[17];
    const float* Wf = (const float*)d_in[18];
    const float* bfv = (const float*)d_in[19];
    float* out = (float*)d_out;

    char* ws = (char*)d_ws;
    u16* h0      = (u16*)(ws + 0);             // 25,600,000
    u16* hA      = (u16*)(ws + 25600000);      // 25,600,000
    u16* hB      = (u16*)(ws + 51200000);      // 25,600,000
    u16* agss    = (u16*)(ws + 76800000);      // 25,600,000
    float* agg2f = (float*)(ws + 102400000);   // 25,600,000
    float* inv_deg = (float*)(ws + 128000000); //    400,000
    int* ro      = (int*)(ws + 128400000);     //    400,016
    int* degcur  = (int*)(ws + 128800016);     //    400,000
    int* csr     = (int*)(ws + 129200016);     //  6,400,000
    int* tsum    = (int*)(ws + 129200016);     // 50,000 (aliases csr head; dead before fill)
    u16* Bp      = (u16*)(ws + 135600016);     //    245,760
    float* b_sum = (float*)(ws + 135845776);   //      1,536

    // ---- CSR build (sub->sub) ----
    hipMemsetAsync(degcur, 0, N_SUB * sizeof(int), stream);
    hist_kernel<<<(E_SS + 255) / 256, 256, 0, stream>>>(ss_dst, degcur, E_SS);
    scan_p1<<<(SCAN_T + 255) / 256, 256, 0, stream>>>(degcur, tsum);
    scan_p2<<<1, 256, 0, stream>>>(tsum);
    scan_p3<<<(SCAN_T + 255) / 256, 256, 0, stream>>>(degcur, tsum, ro, inv_deg);
    fill_kernel<<<(E_SS + 255) / 256, 256, 0, stream>>>(ss_src, ss_dst, degcur, csr, E_SS);

    // ---- layer-invariant hru aggregations (fp32) ----
    hipMemsetAsync(agg2f, 0, (size_t)N_SUB * 64 * sizeof(float), stream);
    scatter32_kernel<<<(E_AS * 8 + 255) / 256, 256, 0, stream>>>(x_agr, as_src, as_dst, agg2f, E_AS, 0);
    scatter32_kernel<<<(E_US * 8 + 255) / 256, 256, 0, stream>>>(x_urb, us_src, us_dst, agg2f, E_US, 32);

    // ---- weight packing + bias sums ----
    build_bp<<<240, 64, 0, stream>>>(Wl_ss, Wr_ss, Wr_as, Wr_us, Wl_as, Wl_us, Bp);
    add3_kernel<<<2, 256, 0, stream>>>(bl_ss, bl_as, bl_us, b_sum, NL * HID);

    // ---- x_sub -> bf16 ----
    cvt_f32_bf16<<<(N_SUB * HID / 4 + 255) / 256, 256, 0, stream>>>(x_sub, h0, N_SUB * HID / 4);

    const int agg_grid = (N_SUB + 3) / 4;
    const int gemm_grid = (N_SUB + 127) / 128;
    const size_t BPL = 40960;  // Bp per-layer stride (u16)

    // ---- layer 0: sum aggregation ----
    agg_ss_bf16<<<agg_grid, 256, 0, stream>>>((const u32*)h0, ro, csr, inv_deg, (u32*)agss, N_SUB, 0);
    layer_gemm_mfma<<<gemm_grid, 256, 0, stream>>>(agss, h0, agg2f, Bp + 0 * BPL, b_sum + 0 * HID, hA, N_SUB);

    // ---- layer 1: mean aggregation ----
    agg_ss_bf16<<<agg_grid, 256, 0, stream>>>((const u32*)hA, ro, csr, inv_deg, (u32*)agss, N_SUB, 1);
    layer_gemm_mfma<<<gemm_grid, 256, 0, stream>>>(agss, hA, agg2f, Bp + 1 * BPL, b_sum + 1 * HID, hB, N_SUB);

    // ---- layer 2: mean aggregation ----
    agg_ss_bf16<<<agg_grid, 256, 0, stream>>>((const u32*)hB, ro, csr, inv_deg, (u32*)agss, N_SUB, 1);
    layer_gemm_mfma<<<gemm_grid, 256, 0, stream>>>(agss, hB, agg2f, Bp + 2 * BPL, b_sum + 2 * HID, hA, N_SUB);

    // ---- final projection + softmax ----
    final_kernel<<<(N_SUB * NOUT + 255) / 256, 256, 0, stream>>>((const u32*)hA, Wf, bfv, out, N_SUB);
}

// Round 5
// 798.408 us; speedup vs baseline: 6.6246x; 1.1654x over previous
//
#include <hip/hip_runtime.h>
#include <hip/hip_bf16.h>

#define N_SUB 100000
#define N_AGR 200000
#define N_URB 100000
#define E_SS  1600000
#define E_AS  400000
#define E_US  200000
#define HID   128
#define DHRU  32
#define NOUT  16
#define NL    3
#define SCAN_T 12500  // N_SUB / 8

typedef unsigned short u16;
typedef unsigned int u32;
typedef short bf16x8 __attribute__((ext_vector_type(8)));
typedef float f32x4 __attribute__((ext_vector_type(4)));

static __device__ __forceinline__ u16 f2b(float f) {
    u32 x = __float_as_uint(f);
    u32 r = (x + 0x7fffu + ((x >> 16) & 1u)) >> 16;  // RNE
    return (u16)r;
}
static __device__ __forceinline__ float blo(u32 u) { return __uint_as_float(u << 16); }
static __device__ __forceinline__ float bhi(u32 u) { return __uint_as_float(u & 0xffff0000u); }

// ---------------- CSR build ----------------

__global__ void hist_kernel(const int* __restrict__ dst, int* __restrict__ deg, int n) {
    int i = blockIdx.x * 256 + threadIdx.x;
    if (i < n) atomicAdd(&deg[dst[i]], 1);
}

// 3-phase parallel exclusive scan over deg[N_SUB]
__global__ void scan_p1(const int* __restrict__ deg, int* __restrict__ tsum) {
    int i = blockIdx.x * 256 + threadIdx.x;
    if (i >= SCAN_T) return;
    const int4* p = (const int4*)(deg + i * 8);
    int4 a = p[0], b = p[1];
    tsum[i] = a.x + a.y + a.z + a.w + b.x + b.y + b.z + b.w;
}

__global__ void scan_p2(int* __restrict__ tsum) {
    __shared__ int sh[256];
    const int tid = threadIdx.x;
    const int start = tid * 49;
    const int end = min(start + 49, SCAN_T);
    int s = 0;
    for (int i = start; i < end; ++i) s += tsum[i];
    sh[tid] = s;
    __syncthreads();
    for (int o = 1; o < 256; o <<= 1) {
        int t = (tid >= o) ? sh[tid - o] : 0;
        __syncthreads();
        sh[tid] += t;
        __syncthreads();
    }
    int off = (tid > 0) ? sh[tid - 1] : 0;
    for (int i = start; i < end; ++i) {
        int v = tsum[i];
        tsum[i] = off;
        off += v;
    }
}

// degcur: deg on entry, cursor on exit; inv_deg optional (null to skip)
__global__ void scan_p3(int* __restrict__ degcur, const int* __restrict__ tsum,
                        int* __restrict__ ro, float* inv_deg) {
    int i = blockIdx.x * 256 + threadIdx.x;
    if (i >= SCAN_T) return;
    int off = tsum[i];
#pragma unroll
    for (int j = 0; j < 8; ++j) {
        int idx = i * 8 + j;
        int d = degcur[idx];
        ro[idx] = off;
        if (inv_deg) inv_deg[idx] = 1.0f / (float)(d > 1 ? d : 1);
        degcur[idx] = off;  // cursor
        off += d;
    }
    if (i == SCAN_T - 1) ro[N_SUB] = off;
}

__global__ void fill_kernel(const int* __restrict__ src, const int* __restrict__ dst,
                            int* __restrict__ cursor, int* __restrict__ csr, int n) {
    int i = blockIdx.x * 256 + threadIdx.x;
    if (i < n) {
        int p = atomicAdd(&cursor[dst[i]], 1);
        csr[p] = src[i];
    }
}

// ---------------- hru aggregation: CSR gather, bf16 out ----------------
// one wave per node; lanes 0..31: as-edges (x_agr), lanes 32..63: us-edges (x_urb)
__global__ __launch_bounds__(256)
void agg2_gather(const float* __restrict__ x_agr, const float* __restrict__ x_urb,
                 const int* __restrict__ ro_as, const int* __restrict__ csr_as,
                 const int* __restrict__ ro_us, const int* __restrict__ csr_us,
                 u16* __restrict__ agg2b, int n) {
    int node = blockIdx.x * 4 + (threadIdx.x >> 6);
    int lane = threadIdx.x & 63;
    if (node >= n) return;
    const bool is_us = lane >= 32;
    const int col = lane & 31;
    const int* ro = is_us ? ro_us : ro_as;
    const int* csr = is_us ? csr_us : csr_as;
    const float* x = is_us ? x_urb : x_agr;
    int beg = ro[node], end = ro[node + 1];
    float acc = 0.f;
    for (int p = beg; p < end; ++p) {
        acc += x[(size_t)csr[p] * 32 + col];
    }
    agg2b[(size_t)node * 64 + lane] = f2b(acc);
}

// ---------------- weight prep ----------------
__global__ void add3_kernel(const float* __restrict__ a, const float* __restrict__ b,
                            const float* __restrict__ c, float* __restrict__ o, int n) {
    int i = blockIdx.x * 256 + threadIdx.x;
    if (i < n) o[i] = a[i] + b[i] + c[i];
}

// Pack stacked [Wl_ss; Wr_ss+Wr_as+Wr_us; Wl_as; Wl_us] (320x128) per layer into
// MFMA B-fragment order: Bp[lay][((s*8+c)*64+lane)*8+j] = W[s*32+(lane>>4)*8+j][c*16+(lane&15)]
__global__ void build_bp(const float* __restrict__ Wl_ss, const float* __restrict__ Wr_ss,
                         const float* __restrict__ Wr_as, const float* __restrict__ Wr_us,
                         const float* __restrict__ Wl_as, const float* __restrict__ Wl_us,
                         u16* __restrict__ Bp) {
    int b = blockIdx.x;           // 3*10*8 = 240
    int lane = threadIdx.x;       // 64
    int lay = b / 80, rem = b % 80, s = rem / 8, c = rem % 8;
    int col = c * 16 + (lane & 15);
    u16* o = Bp + (size_t)(((lay * 80) + s * 8 + c) * 64 + lane) * 8;
#pragma unroll
    for (int j = 0; j < 8; ++j) {
        int k = s * 32 + (lane >> 4) * 8 + j;
        float v;
        if (k < 128) {
            v = Wl_ss[((size_t)lay * 128 + k) * 128 + col];
        } else if (k < 256) {
            size_t idx = ((size_t)lay * 128 + (k - 128)) * 128 + col;
            v = Wr_ss[idx] + Wr_as[idx] + Wr_us[idx];
        } else if (k < 288) {
            v = Wl_as[((size_t)lay * 32 + (k - 256)) * 128 + col];
        } else {
            v = Wl_us[((size_t)lay * 32 + (k - 288)) * 128 + col];
        }
        o[j] = f2b(v);
    }
}

// ---------------- fp32 -> bf16 convert (x_sub -> h0) ----------------
__global__ void cvt_f32_bf16(const float* __restrict__ in, u16* __restrict__ o, int n4) {
    int i = blockIdx.x * 256 + threadIdx.x;
    if (i >= n4) return;
    float4 v = ((const float4*)in)[i];
    ushort4 u;
    u.x = f2b(v.x); u.y = f2b(v.y); u.z = f2b(v.z); u.w = f2b(v.w);
    ((ushort4*)o)[i] = u;
}

// ---------------- per-layer CSR gather aggregation (bf16 in/out, fp32 accum) ----------------
__global__ __launch_bounds__(256)
void agg_ss_bf16(const u32* __restrict__ h32, const int* __restrict__ ro,
                 const int* __restrict__ csr, const float* __restrict__ inv_deg,
                 u32* __restrict__ out32, int n, int use_mean) {
    int node = blockIdx.x * 4 + (threadIdx.x >> 6);
    int lane = threadIdx.x & 63;
    if (node >= n) return;
    int beg = ro[node], end = ro[node + 1];
    float a0 = 0.f, a1 = 0.f;
    int p = beg;
    for (; p + 1 < end; p += 2) {
        int s0 = csr[p], s1 = csr[p + 1];
        u32 u0 = h32[(size_t)s0 * 64 + lane];
        u32 u1 = h32[(size_t)s1 * 64 + lane];
        a0 += blo(u0) + blo(u1);
        a1 += bhi(u0) + bhi(u1);
    }
    if (p < end) {
        u32 u0 = h32[(size_t)csr[p] * 64 + lane];
        a0 += blo(u0);
        a1 += bhi(u0);
    }
    if (use_mean) {
        float iv = inv_deg[node];
        a0 *= iv; a1 *= iv;
    }
    out32[(size_t)node * 64 + lane] = (u32)f2b(a0) | ((u32)f2b(a1) << 16);
}

// ---------------- fused layer GEMM via MFMA bf16 ----------------
// out = relu([agss(128) | h(128) | agg2b(64)] @ Bp + bsum), 128 rows/block, 4 waves
__global__ __launch_bounds__(256)
void layer_gemm_mfma(const u16* __restrict__ agss, const u16* __restrict__ h,
                     const u16* __restrict__ agg2b, const u16* __restrict__ Bp,
                     const float* __restrict__ bsum, u16* __restrict__ out, int n) {
    __shared__ __align__(16) u16 tile[4][32][136];
    const int tid = threadIdx.x;
    const int w = tid >> 6, l = tid & 63;
    const int lr = l & 15, lq = l >> 4;
    const int rows0 = blockIdx.x * 128 + w * 32;

    f32x4 acc[2][8];
#pragma unroll
    for (int rf = 0; rf < 2; ++rf)
#pragma unroll
        for (int c = 0; c < 8; ++c) acc[rf][c] = (f32x4){0.f, 0.f, 0.f, 0.f};

    const bf16x8 zf = {0, 0, 0, 0, 0, 0, 0, 0};

#pragma unroll
    for (int s = 0; s < 10; ++s) {
        const u16* X;
        int ld, koff;
        if (s < 4)      { X = agss;  ld = 128; koff = s * 32 + lq * 8; }
        else if (s < 8) { X = h;     ld = 128; koff = (s - 4) * 32 + lq * 8; }
        else            { X = agg2b; ld = 64;  koff = (s - 8) * 32 + lq * 8; }
        bf16x8 a[2];
#pragma unroll
        for (int rf = 0; rf < 2; ++rf) {
            int row = rows0 + rf * 16 + lr;
            a[rf] = (row < n) ? *(const bf16x8*)(X + (size_t)row * ld + koff) : zf;
        }
        const u16* bp = Bp + ((size_t)(s * 8) * 64 + l) * 8;
#pragma unroll
        for (int c = 0; c < 8; ++c) {
            bf16x8 b = *(const bf16x8*)(bp + (size_t)c * 64 * 8);
            acc[0][c] = __builtin_amdgcn_mfma_f32_16x16x32_bf16(a[0], b, acc[0][c], 0, 0, 0);
            acc[1][c] = __builtin_amdgcn_mfma_f32_16x16x32_bf16(a[1], b, acc[1][c], 0, 0, 0);
        }
    }

    float bias[8];
#pragma unroll
    for (int c = 0; c < 8; ++c) bias[c] = bsum[c * 16 + lr];

#pragma unroll
    for (int rf = 0; rf < 2; ++rf)
#pragma unroll
        for (int c = 0; c < 8; ++c)
#pragma unroll
            for (int r = 0; r < 4; ++r) {
                float v = fmaxf(acc[rf][c][r] + bias[c], 0.f);
                tile[w][rf * 16 + lq * 4 + r][c * 16 + lr] = f2b(v);
            }

#pragma unroll
    for (int i = 0; i < 8; ++i) {
        int row = i * 4 + lq;
        int grow = rows0 + row;
        if (grow < n)
            *(bf16x8*)(out + (size_t)grow * 128 + lr * 8) =
                *(const bf16x8*)&tile[w][row][lr * 8];
    }
}

// ---------------- final projection + softmax (bf16 h, fp32 out) ----------------
__global__ __launch_bounds__(256)
void final_kernel(const u32* __restrict__ h32, const float* __restrict__ Wf,
                  const float* __restrict__ bfv, float* __restrict__ out, int n) {
    __shared__ float wsh[HID * NOUT + NOUT];
    for (int i = threadIdx.x; i < HID * NOUT; i += 256) wsh[i] = Wf[i];
    if (threadIdx.x < NOUT) wsh[HID * NOUT + threadIdx.x] = bfv[threadIdx.x];
    __syncthreads();
    int t = blockIdx.x * 256 + threadIdx.x;
    int node = t >> 4, c = t & 15;
    if (node >= n) return;
    const u32* hr = h32 + (size_t)node * 64;
    float acc = wsh[HID * NOUT + c];
#pragma unroll 4
    for (int k2 = 0; k2 < 64; ++k2) {
        u32 u = hr[k2];
        acc += blo(u) * wsh[(2 * k2) * NOUT + c] + bhi(u) * wsh[(2 * k2 + 1) * NOUT + c];
    }
    float m = acc;
#pragma unroll
    for (int o = 8; o >= 1; o >>= 1) m = fmaxf(m, __shfl_xor(m, o, 16));
    float e = expf(acc - m);
    float ssum = e;
#pragma unroll
    for (int o = 8; o >= 1; o >>= 1) ssum += __shfl_xor(ssum, o, 16);
    out[(size_t)node * NOUT + c] = e / ssum;
}

extern "C" void kernel_launch(void* const* d_in, const int* in_sizes, int n_in,
                              void* d_out, int out_size, void* d_ws, size_t ws_size,
                              hipStream_t stream) {
    const float* x_sub = (const float*)d_in[0];
    const float* x_agr = (const float*)d_in[1];
    const float* x_urb = (const float*)d_in[2];
    const int* ss_src = (const int*)d_in[3];
    const int* ss_dst = (const int*)d_in[4];
    const int* as_src = (const int*)d_in[5];
    const int* as_dst = (const int*)d_in[6];
    const int* us_src = (const int*)d_in[7];
    const int* us_dst = (const int*)d_in[8];
    const float* Wl_ss = (const float*)d_in[9];
    const float* bl_ss = (const float*)d_in[10];
    const float* Wr_ss = (const float*)d_in[11];
    const float* Wl_as = (const float*)d_in[12];
    const float* bl_as = (const float*)d_in[13];
    const float* Wr_as = (const float*)d_in[14];
    const float* Wl_us = (const float*)d_in[15];
    const float* bl_us = (const float*)d_in[16];
    const float* Wr_us = (const float*)d_in[17];
    const float* Wf = (const float*)d_in[18];
    const float* bfv = (const float*)d_in[19];
    float* out = (float*)d_out;

    char* ws = (char*)d_ws;
    u16* h0      = (u16*)(ws + 0);             // 25,600,000
    u16* hA      = (u16*)(ws + 25600000);      // 25,600,000
    u16* hB      = (u16*)(ws + 51200000);      // 25,600,000
    u16* agss    = (u16*)(ws + 76800000);      // 25,600,000
    u16* agg2b   = (u16*)(ws + 102400000);     // 12,800,000
    float* inv_deg = (float*)(ws + 115200000); //    400,000
    int* ro_ss   = (int*)(ws + 115600000);     //    400,016
    int* ro_as   = (int*)(ws + 116000016);     //    400,016
    int* ro_us   = (int*)(ws + 116400032);     //    400,016
    int* deg_ss  = (int*)(ws + 116800048);     //    400,000  } one
    int* deg_as  = (int*)(ws + 117200048);     //    400,000  } contiguous
    int* deg_us  = (int*)(ws + 117600048);     //    400,000  } memset
    int* csr_ss  = (int*)(ws + 118000048);     //  6,400,000
    int* csr_as  = (int*)(ws + 124400048);     //  1,600,000
    int* csr_us  = (int*)(ws + 126000048);     //    800,000
    int* tsum    = (int*)(ws + 126800048);     //     50,000
    u16* Bp      = (u16*)(ws + 126850048);     //    245,760
    float* b_sum = (float*)(ws + 127095808);   //      1,536

    // ---- degree histograms (single memset across the 3 deg arrays) ----
    hipMemsetAsync(deg_ss, 0, 3 * N_SUB * sizeof(int), stream);
    hist_kernel<<<(E_SS + 255) / 256, 256, 0, stream>>>(ss_dst, deg_ss, E_SS);
    hist_kernel<<<(E_AS + 255) / 256, 256, 0, stream>>>(as_dst, deg_as, E_AS);
    hist_kernel<<<(E_US + 255) / 256, 256, 0, stream>>>(us_dst, deg_us, E_US);

    // ---- scans (sequential reuse of tsum) ----
    const int scan_grid = (SCAN_T + 255) / 256;
    scan_p1<<<scan_grid, 256, 0, stream>>>(deg_ss, tsum);
    scan_p2<<<1, 256, 0, stream>>>(tsum);
    scan_p3<<<scan_grid, 256, 0, stream>>>(deg_ss, tsum, ro_ss, inv_deg);
    scan_p1<<<scan_grid, 256, 0, stream>>>(deg_as, tsum);
    scan_p2<<<1, 256, 0, stream>>>(tsum);
    scan_p3<<<scan_grid, 256, 0, stream>>>(deg_as, tsum, ro_as, nullptr);
    scan_p1<<<scan_grid, 256, 0, stream>>>(deg_us, tsum);
    scan_p2<<<1, 256, 0, stream>>>(tsum);
    scan_p3<<<scan_grid, 256, 0, stream>>>(deg_us, tsum, ro_us, nullptr);

    // ---- fills ----
    fill_kernel<<<(E_SS + 255) / 256, 256, 0, stream>>>(ss_src, ss_dst, deg_ss, csr_ss, E_SS);
    fill_kernel<<<(E_AS + 255) / 256, 256, 0, stream>>>(as_src, as_dst, deg_as, csr_as, E_AS);
    fill_kernel<<<(E_US + 255) / 256, 256, 0, stream>>>(us_src, us_dst, deg_us, csr_us, E_US);

    // ---- layer-invariant hru aggregation (gather, bf16 out) ----
    agg2_gather<<<(N_SUB + 3) / 4, 256, 0, stream>>>(x_agr, x_urb, ro_as, csr_as,
                                                     ro_us, csr_us, agg2b, N_SUB);

    // ---- weight packing + bias sums ----
    build_bp<<<240, 64, 0, stream>>>(Wl_ss, Wr_ss, Wr_as, Wr_us, Wl_as, Wl_us, Bp);
    add3_kernel<<<2, 256, 0, stream>>>(bl_ss, bl_as, bl_us, b_sum, NL * HID);

    // ---- x_sub -> bf16 ----
    cvt_f32_bf16<<<(N_SUB * HID / 4 + 255) / 256, 256, 0, stream>>>(x_sub, h0, N_SUB * HID / 4);

    const int agg_grid = (N_SUB + 3) / 4;
    const int gemm_grid = (N_SUB + 127) / 128;
    const size_t BPL = 40960;  // Bp per-layer stride (u16)

    // ---- layer 0: sum aggregation ----
    agg_ss_bf16<<<agg_grid, 256, 0, stream>>>((const u32*)h0, ro_ss, csr_ss, inv_deg, (u32*)agss, N_SUB, 0);
    layer_gemm_mfma<<<gemm_grid, 256, 0, stream>>>(agss, h0, agg2b, Bp + 0 * BPL, b_sum + 0 * HID, hA, N_SUB);

    // ---- layer 1: mean aggregation ----
    agg_ss_bf16<<<agg_grid, 256, 0, stream>>>((const u32*)hA, ro_ss, csr_ss, inv_deg, (u32*)agss, N_SUB, 1);
    layer_gemm_mfma<<<gemm_grid, 256, 0, stream>>>(agss, hA, agg2b, Bp + 1 * BPL, b_sum + 1 * HID, hB, N_SUB);

    // ---- layer 2: mean aggregation ----
    agg_ss_bf16<<<agg_grid, 256, 0, stream>>>((const u32*)hB, ro_ss, csr_ss, inv_deg, (u32*)agss, N_SUB, 1);
    layer_gemm_mfma<<<gemm_grid, 256, 0, stream>>>(agss, hB, agg2b, Bp + 2 * BPL, b_sum + 2 * HID, hA, N_SUB);

    // ---- final projection + softmax ----
    final_kernel<<<(N_SUB * NOUT + 255) / 256, 256, 0, stream>>>((const u32*)hA, Wf, bfv, out, N_SUB);
}